// Round 9
// baseline (168.054 us; speedup 1.0000x reference)
//
#include <hip/hip_runtime.h>

// DWT Haar 2x2 block transform:
//   in : (32, 3, 512, 512) fp32
//   out: (32, 12, 256, 256) fp32, sub-band order per (b,c): LL, LH, HL, HH
//
// v8: final cell of the cache-policy matrix — NT LOADS + REGULAR STORES on
// the v7 single-touch structure. Measured matrix so far (harness us):
//   reg/reg 172.1 | reg/nt 174.1 | nt/nt 167.2 (166.0 single-touch) | nt/reg ?
// v1<->v6 (reg loads fixed) showed nt stores cost ~+2us; if additive,
// nt/reg lands ~164. Regular stores allocate the 100MB output in L3 whose
// victims are clean poison lines (free evictions), letting the write
// stream drain lazily instead of nt's forced in-line HBM streaming.
// Structure unchanged from v7 (best variant): lane-linear single-touch nt
// loads, shuffle pair-exchange, 16B/lane dense stores, v1 arithmetic order
// (absmax 0.0). Falsified axes: VMEM shape (v1==v2), MLP depth (v4),
// pipelining (v5), L3-resident-input (v6), line-touch multiplicity
// (v7: -2% only). If this cell is neutral -> policy matrix complete ->
// ROOFLINE (~3.8 TB/s mixed R+W in post-poison-fill harness state).

typedef float v4f __attribute__((ext_vector_type(4)));

#define B_   32
#define C_   3
#define H_   512
#define W_   512
#define HO_  (H_/2)            // 256
#define WO_  (W_/2)            // 256
#define CHUNKS_ (W_/4)         // 128 input 16B-chunks per row
#define PLANE_ (HO_*WO_)       // 65536 floats per sub-band plane
#define NTHREADS_TOTAL (B_*C_*HO_*CHUNKS_)   // 3,145,728

__global__ __launch_bounds__(256) void dwt_haar_kernel(
        const float* __restrict__ x, float* __restrict__ out) {
    int g = blockIdx.x * blockDim.x + threadIdx.x;
    // decompose: g = ((bc*256 + h)*128 + chunk)
    int chunk = g & (CHUNKS_ - 1);          // 16B chunk in input row, 0..127
    int t     = g >> 7;
    int h     = t & (HO_ - 1);              // output row, 0..255
    int bc    = t >> 8;                     // b*3 + c, 0..95

    // Lane-linear nt loads: one instruction covers 1KB dense per wave;
    // every 64B line touched by exactly one instruction.
    const v4f* r0 = reinterpret_cast<const v4f*>(
        x + ((size_t)bc * H_ + 2 * (size_t)h) * W_) + chunk;
    v4f a0 = __builtin_nontemporal_load(r0);            // row 2h
    v4f a1 = __builtin_nontemporal_load(r0 + W_ / 4);   // row 2h+1

    // Haar, v1's exact left-to-right ordering: (a + b + c + d) * 0.5f
    float ll0 = (a0.x + a0.y + a1.x + a1.y) * 0.5f;
    float lh0 = (a0.x + a0.y - a1.x - a1.y) * 0.5f;
    float hl0 = (a0.x - a0.y + a1.x - a1.y) * 0.5f;
    float hh0 = (a0.x - a0.y - a1.x + a1.y) * 0.5f;

    float ll1 = (a0.z + a0.w + a1.z + a1.w) * 0.5f;
    float lh1 = (a0.z + a0.w - a1.z - a1.w) * 0.5f;
    float hl1 = (a0.z - a0.w + a1.z - a1.w) * 0.5f;
    float hh1 = (a0.z - a0.w - a1.z + a1.w) * 0.5f;

    // Pair exchange: even lane assembles LL & HL 16B vectors, odd lane LH & HH.
    int par = chunk & 1;
    float g1a = par ? ll0 : lh0;
    float g1b = par ? ll1 : lh1;
    float r1a = __shfl_xor(g1a, 1);
    float r1b = __shfl_xor(g1b, 1);
    float g2a = par ? hl0 : hh0;
    float g2b = par ? hl1 : hh1;
    float r2a = __shfl_xor(g2a, 1);
    float r2b = __shfl_xor(g2b, 1);

    v4f o1, o2;
    if (par == 0) {
        o1.x = ll0; o1.y = ll1; o1.z = r1a; o1.w = r1b;   // LL cols 4j..4j+3
        o2.x = hl0; o2.y = hl1; o2.z = r2a; o2.w = r2b;   // HL cols 4j..4j+3
    } else {
        o1.x = r1a; o1.y = r1b; o1.z = lh0; o1.w = lh1;   // LH cols 4j..4j+3
        o2.x = r2a; o2.y = r2b; o2.z = hh0; o2.w = hh1;   // HH cols 4j..4j+3
    }

    int b = bc / C_;
    int c = bc - b * C_;
    int j = chunk >> 1;        // 16B block in output row, 0..63
    // REGULAR stores (the one policy cell untested): allocate in L3 whose
    // victims are clean poison lines; lazy drain vs nt's in-line streaming.
    v4f* o = reinterpret_cast<v4f*>(
        out + (((size_t)b * (C_ * 4) + c * 4 + par) * HO_ + h) * WO_
            + 4 * (size_t)j);
    o[0]                = o1;
    o[2 * (PLANE_ / 4)] = o2;   // +2 planes
}

extern "C" void kernel_launch(void* const* d_in, const int* in_sizes, int n_in,
                              void* d_out, int out_size, void* d_ws, size_t ws_size,
                              hipStream_t stream) {
    const float* x = (const float*)d_in[0];
    float* out = (float*)d_out;
    dim3 block(256);
    dim3 grid(NTHREADS_TOTAL / 256);   // 12288 blocks
    dwt_haar_kernel<<<grid, block, 0, stream>>>(x, out);
}

// Round 10
// 166.823 us; speedup vs baseline: 1.0074x; 1.0074x over previous
//
#include <hip/hip_runtime.h>

// DWT Haar 2x2 block transform:
//   in : (32, 3, 512, 512) fp32
//   out: (32, 12, 256, 256) fp32, sub-band order per (b,c): LL, LH, HL, HH
//
// v9 = v7 reverted (best measured: 166.0 us harness, absmax 0.0).
// Final kernel. Cache-policy matrix complete (harness us):
//   reg/reg 172.1 | reg/nt 174.1 | nt/reg 168.1 | nt/nt 167.2 | nt/nt+single-touch 166.0
// Structure: lane-linear single-touch nt loads (1KB dense per instr/wave),
// shuffle pair-exchange (__shfl_xor(.,1) quad-perm) so every store is a
// dense 16B/lane dwordx4, nt on both streams, v1 arithmetic order.
// Falsified axes (all within ±3% unless noted): VMEM instr shape (v1==v2),
// per-wave MLP depth (v4), phase-wall pipelining / persistent waves (v5),
// L3-resident input via reg loads (v6), line-touch multiplicity (v7 -1%),
// nt-load/reg-store interaction (v8, -2us regression).
// Remaining gap to the 6.29 TB/s clean-state copy ceiling (~3.8 vs 6.3
// TB/s mixed R+W) is a property of the post-poison-fill harness state,
// not kernel-controllable structure. ROOFLINE.

typedef float v4f __attribute__((ext_vector_type(4)));

#define B_   32
#define C_   3
#define H_   512
#define W_   512
#define HO_  (H_/2)            // 256
#define WO_  (W_/2)            // 256
#define CHUNKS_ (W_/4)         // 128 input 16B-chunks per row
#define PLANE_ (HO_*WO_)       // 65536 floats per sub-band plane
#define NTHREADS_TOTAL (B_*C_*HO_*CHUNKS_)   // 3,145,728

__global__ __launch_bounds__(256) void dwt_haar_kernel(
        const float* __restrict__ x, float* __restrict__ out) {
    int g = blockIdx.x * blockDim.x + threadIdx.x;
    // decompose: g = ((bc*256 + h)*128 + chunk)
    int chunk = g & (CHUNKS_ - 1);          // 16B chunk in input row, 0..127
    int t     = g >> 7;
    int h     = t & (HO_ - 1);              // output row, 0..255
    int bc    = t >> 8;                     // b*3 + c, 0..95

    // Lane-linear nt loads: one instruction covers 1KB dense per wave;
    // every 64B line touched by exactly one instruction.
    const v4f* r0 = reinterpret_cast<const v4f*>(
        x + ((size_t)bc * H_ + 2 * (size_t)h) * W_) + chunk;
    v4f a0 = __builtin_nontemporal_load(r0);            // row 2h
    v4f a1 = __builtin_nontemporal_load(r0 + W_ / 4);   // row 2h+1

    // Haar, v1's exact left-to-right ordering: (a + b + c + d) * 0.5f
    float ll0 = (a0.x + a0.y + a1.x + a1.y) * 0.5f;
    float lh0 = (a0.x + a0.y - a1.x - a1.y) * 0.5f;
    float hl0 = (a0.x - a0.y + a1.x - a1.y) * 0.5f;
    float hh0 = (a0.x - a0.y - a1.x + a1.y) * 0.5f;

    float ll1 = (a0.z + a0.w + a1.z + a1.w) * 0.5f;
    float lh1 = (a0.z + a0.w - a1.z - a1.w) * 0.5f;
    float hl1 = (a0.z - a0.w + a1.z - a1.w) * 0.5f;
    float hh1 = (a0.z - a0.w - a1.z + a1.w) * 0.5f;

    // Pair exchange: even lane assembles LL & HL 16B vectors, odd lane LH & HH.
    int par = chunk & 1;
    float g1a = par ? ll0 : lh0;
    float g1b = par ? ll1 : lh1;
    float r1a = __shfl_xor(g1a, 1);
    float r1b = __shfl_xor(g1b, 1);
    float g2a = par ? hl0 : hh0;
    float g2b = par ? hl1 : hh1;
    float r2a = __shfl_xor(g2a, 1);
    float r2b = __shfl_xor(g2b, 1);

    v4f o1, o2;
    if (par == 0) {
        o1.x = ll0; o1.y = ll1; o1.z = r1a; o1.w = r1b;   // LL cols 4j..4j+3
        o2.x = hl0; o2.y = hl1; o2.z = r2a; o2.w = r2b;   // HL cols 4j..4j+3
    } else {
        o1.x = r1a; o1.y = r1b; o1.z = lh0; o1.w = lh1;   // LH cols 4j..4j+3
        o2.x = r2a; o2.y = r2b; o2.z = hh0; o2.w = hh1;   // HH cols 4j..4j+3
    }

    int b = bc / C_;
    int c = bc - b * C_;
    int j = chunk >> 1;        // 16B block in output row, 0..63
    // store 1 -> plane c*4 + par (LL or LH); store 2 -> plane c*4 + 2 + par
    v4f* o = reinterpret_cast<v4f*>(
        out + (((size_t)b * (C_ * 4) + c * 4 + par) * HO_ + h) * WO_
            + 4 * (size_t)j);
    __builtin_nontemporal_store(o1, o);
    __builtin_nontemporal_store(o2, o + 2 * (PLANE_ / 4));   // +2 planes
}

extern "C" void kernel_launch(void* const* d_in, const int* in_sizes, int n_in,
                              void* d_out, int out_size, void* d_ws, size_t ws_size,
                              hipStream_t stream) {
    const float* x = (const float*)d_in[0];
    float* out = (float*)d_out;
    dim3 block(256);
    dim3 grid(NTHREADS_TOTAL / 256);   // 12288 blocks
    dwt_haar_kernel<<<grid, block, 0, stream>>>(x, out);
}